// Round 1
// baseline (16119.023 us; speedup 1.0000x reference)
//
#include <hip/hip_runtime.h>

constexpr int BB = 32;
constexpr int TT = 512;
constexpr size_t MSZ = (size_t)BB * TT * 128;           // one embedding array (floats)
constexpr size_t M_OFF = 0;                              // 3 * MSZ
constexpr size_t MASK_OFF = 3 * MSZ;                     // 3*B*T ints
constexpr size_t SUM_OFF = MASK_OFF + (size_t)3 * BB * TT;   // 4 * MSZ
constexpr size_t WT_OFF = SUM_OFF + 4 * MSZ;             // 512*1024 floats, [k][hid][gate]
constexpr size_t FSEL_OFF = WT_OFF + (size_t)512 * 1024; // 4*32*256 floats

__device__ __forceinline__ float sigm(float x) {
  return __builtin_amdgcn_rcpf(1.f + __builtin_amdgcn_exp2f(-1.44269504f * x));
}
__device__ __forceinline__ float tanhfast(float x) {
  float e = __builtin_amdgcn_exp2f(2.88539008f * x);
  return 1.f - 2.f * __builtin_amdgcn_rcpf(e + 1.f);
}
__device__ __forceinline__ float leaky(float x) { return x >= 0.f ? x : 0.1f * x; }

// m = leaky(xy @ W_mlp^T + b_mlp), one thread per output element
__global__ __launch_bounds__(256) void embed_kernel(
    const float* __restrict__ a, const float* __restrict__ t,
    const float* __restrict__ n, const float* __restrict__ Wm,
    const float* __restrict__ bm, float* __restrict__ ws) {
  int idx = blockIdx.x * 256 + threadIdx.x;   // < 3*B*T*128
  int h = idx & 127;
  int bt = idx >> 7;
  int traj = bt / (BB * TT);
  int r = bt - traj * (BB * TT);
  const float* src = traj == 0 ? a : (traj == 1 ? t : n);
  float x0 = src[r * 4 + 0], x1 = src[r * 4 + 1];
  float v = x0 * Wm[2 * h] + x1 * Wm[2 * h + 1] + bm[h];
  ws[M_OFF + (size_t)traj * MSZ + (size_t)r * 128 + h] = leaky(v);
}

// grid-id mask: valid iff gy*128 + gx - 257 >= 1 (integral floats)
__global__ __launch_bounds__(256) void mask_kernel(
    const float* __restrict__ a, const float* __restrict__ t,
    const float* __restrict__ n, float* __restrict__ ws) {
  int idx = blockIdx.x * 256 + threadIdx.x;   // < 3*B*T
  int traj = idx / (BB * TT);
  int r = idx - traj * (BB * TT);
  const float* src = traj == 0 ? a : (traj == 1 ? t : n);
  float gx = src[r * 4 + 2], gy = src[r * 4 + 3];
  ((int*)(ws + MASK_OFF))[idx] = (gy * 128.f + gx - 257.f) >= 0.5f ? 1 : 0;
}

// pre-transpose [Wih | Whh] (torch gate order i,f,g,o) to [k][hid][gate] so the
// LSTM inner loop does one coalesced float4 load per (k, hidden unit)
__global__ __launch_bounds__(256) void wt_kernel(
    const float* __restrict__ Wih, const float* __restrict__ Whh,
    float* __restrict__ ws) {
  int idx = blockIdx.x * 256 + threadIdx.x;  // < 512*1024
  int k = idx >> 10;
  int rest = idx & 1023;
  int hid = rest >> 2, g = rest & 3;
  int row = g * 256 + hid;
  float v = (k < 256) ? Wih[row * 256 + k] : Whh[row * 256 + (k - 256)];
  ws[WT_OFF + idx] = v;
}

// one WG per (job, batch, 16-row t-tile); job 0..3 = L0..L3 source/dest pairs
__global__ __launch_bounds__(256) void attn_kernel(float* __restrict__ ws) {
  __shared__ float srcL[16][129];
  __shared__ float dtile[128][34];     // transposed dst tile [k][s], S_TILE=32
  __shared__ float scoresL[16][514];
  __shared__ float rowscaleL[16];
  __shared__ int maskD[32];
  __shared__ int maskS[16];

  int tid = threadIdx.x;
  int job = blockIdx.x >> 10;
  int rem = blockIdx.x & 1023;
  int b = rem >> 5, ttile = rem & 31;
  int t0 = ttile * 16;
  int srcTr = (job == 1) ? 1 : ((job == 3) ? 2 : 0);
  int dstTr = (job == 0) ? 1 : ((job == 2) ? 2 : 0);
  const float* msrc = ws + M_OFF + (size_t)srcTr * MSZ + (size_t)b * TT * 128;
  const float* mdst = ws + M_OFF + (size_t)dstTr * MSZ + (size_t)b * TT * 128;
  const int* maskbase = (const int*)(ws + MASK_OFF);
  const int* smask = maskbase + srcTr * BB * TT + b * TT;
  const int* dmask = maskbase + dstTr * BB * TT + b * TT;
  float* out = ws + SUM_OFF + (size_t)job * MSZ + (size_t)b * TT * 128;

  for (int i = 0; i < 8; i++) {
    int idx = i * 256 + tid;
    int tr = idx >> 7, k = idx & 127;
    srcL[tr][k] = msrc[(size_t)(t0 + tr) * 128 + k];
  }
  if (tid < 16) maskS[tid] = smask[t0 + tid];
  __syncthreads();

  // pass 1: scores (invalid dst -> -1e9, exact ref semantics)
  int s2 = tid & 15, trr = tid >> 4;
  for (int st = 0; st < 16; st++) {
    int s0 = st * 32;
    for (int i = 0; i < 16; i++) {
      int idx = i * 256 + tid;
      int s = idx >> 7, k = idx & 127;
      dtile[k][s] = mdst[(size_t)(s0 + s) * 128 + k];
    }
    if (tid < 32) maskD[tid] = dmask[s0 + tid];
    __syncthreads();
    float d0 = 0.f, d1 = 0.f;
#pragma unroll 8
    for (int k = 0; k < 128; k++) {
      float sv = srcL[trr][k];
      float2 dv = *(const float2*)&dtile[k][2 * s2];
      d0 += sv * dv.x;
      d1 += sv * dv.y;
    }
    scoresL[trr][s0 + 2 * s2]     = maskD[2 * s2]     ? d0 : -1e9f;
    scoresL[trr][s0 + 2 * s2 + 1] = maskD[2 * s2 + 1] ? d1 : -1e9f;
    __syncthreads();
  }

  // softmax per row; invalid entries underflow to 0 exactly like the reference.
  // invalid src row or all-invalid dst -> rowscale 0 (pa row = 0)
  {
    int r = tid >> 4, j = tid & 15;  // 16 threads per row, same wave
    float mx = -3.0e38f;
    for (int i = 0; i < 32; i++) mx = fmaxf(mx, scoresL[r][j + 16 * i]);
    for (int m = 1; m < 16; m <<= 1) mx = fmaxf(mx, __shfl_xor(mx, m, 64));
    float den = 0.f;
    for (int i = 0; i < 32; i++) {
      float p = __builtin_amdgcn_exp2f((scoresL[r][j + 16 * i] - mx) * 1.44269504f);
      scoresL[r][j + 16 * i] = p;
      den += p;
    }
    for (int m = 1; m < 16; m <<= 1) den += __shfl_xor(den, m, 64);
    if (j == 0) rowscaleL[r] = (maskS[r] && mx > -5e8f) ? (1.f / den) : 0.f;
  }
  __syncthreads();

  // pass 2: weighted sum over dst
  int kk = tid & 127, tix = tid >> 7;
  float acc[8];
#pragma unroll
  for (int u = 0; u < 8; u++) acc[u] = 0.f;
  for (int st = 0; st < 16; st++) {
    int s0 = st * 32;
    for (int i = 0; i < 16; i++) {
      int idx = i * 256 + tid;
      int s = idx >> 7, k = idx & 127;
      dtile[k][s] = mdst[(size_t)(s0 + s) * 128 + k];
    }
    __syncthreads();
    for (int s = 0; s < 32; s += 2) {
      float2 dv = *(const float2*)&dtile[kk][s];
#pragma unroll
      for (int u = 0; u < 8; u++) {
        float2 p = *(const float2*)&scoresL[tix * 8 + u][s0 + s];
        acc[u] += p.x * dv.x + p.y * dv.y;
      }
    }
    __syncthreads();
  }
#pragma unroll
  for (int u = 0; u < 8; u++) {
    int tr = tix * 8 + u;
    out[(size_t)(t0 + tr) * 128 + kk] = acc[u] * rowscaleL[tr];
  }
}

// 64 WGs x 512 threads; WG owns 2 sequences (seq = l*32+b, l in {p1a,p1b,p2a,p2b}).
// h/c stay on-CU (LDS/regs); weights streamed coalesced from L2 every step.
__global__ __launch_bounds__(512) void lstm_kernel(
    float* __restrict__ ws, const int* __restrict__ la,
    const int* __restrict__ lt, const int* __restrict__ ln,
    const float* __restrict__ bih, const float* __restrict__ bhh) {
  __shared__ float xh[2][512];    // per local seq: [0:256)=x_t, [256:512)=h_{t-1}
  int tid = threadIdx.x;
  int sl = tid >> 8;
  int hid = tid & 255;
  int seq = blockIdx.x * 2 + sl;
  int l = seq >> 5, b = seq & 31;
  int srcTr = (l == 1) ? 1 : ((l == 3) ? 2 : 0);
  const float* xrow = ws + M_OFF + (size_t)srcTr * MSZ + (size_t)b * TT * 128;
  const float* srow = ws + SUM_OFF + (size_t)l * MSZ + (size_t)b * TT * 128;
  const int* lens = (l == 1) ? lt : ((l == 3) ? ln : la);
  int mylen = lens[b];
  const float* Wt = ws + WT_OFF;
  float bi = bih[hid] + bhh[hid];
  float bf = bih[256 + hid] + bhh[256 + hid];
  float bg = bih[512 + hid] + bhh[512 + hid];
  float bo = bih[768 + hid] + bhh[768 + hid];
  float c = 0.f;
  xh[sl][256 + hid] = 0.f;
  float* fout = ws + FSEL_OFF + (size_t)seq * 256;
  const float* wp = Wt + (hid << 2);
  for (int t = 0; t < TT; t++) {
    float v;
    if (hid < 128) {
      v = xrow[t * 128 + hid];
    } else {
      int k2 = hid - 128;
      v = xrow[t * 128 + k2] - srow[t * 128 + k2];
    }
    xh[sl][hid] = v;
    __syncthreads();                 // x_t and h_{t-1} visible
    float ai = bi, af = bf, ag = bg, ao = bo;
    const float* xp = &xh[sl][0];
    for (int k = 0; k < 512; k += 4) {
      float4 xv = *(const float4*)(xp + k);
      const float* w = wp + (size_t)k * 1024;
      float4 w0 = *(const float4*)(w);
      float4 w1 = *(const float4*)(w + 1024);
      float4 w2 = *(const float4*)(w + 2048);
      float4 w3 = *(const float4*)(w + 3072);
      ai += xv.x * w0.x + xv.y * w1.x + xv.z * w2.x + xv.w * w3.x;
      af += xv.x * w0.y + xv.y * w1.y + xv.z * w2.y + xv.w * w3.y;
      ag += xv.x * w0.z + xv.y * w1.z + xv.z * w2.z + xv.w * w3.z;
      ao += xv.x * w0.w + xv.y * w1.w + xv.z * w2.w + xv.w * w3.w;
    }
    float gi = sigm(ai), gf = sigm(af), gg = tanhfast(ag), go = sigm(ao);
    c = gf * c + gi * gg;
    float h = go * tanhfast(c);
    __syncthreads();                 // all gate loops done reading old h
    xh[sl][256 + hid] = h;
    if (t == mylen - 1) fout[hid] = h;
  }
}

// gate head on a-side + pairwise distance + exp
__global__ __launch_bounds__(256) void finish_kernel(
    const float* __restrict__ ws, const float* __restrict__ W1,
    const float* __restrict__ b1, const float* __restrict__ W2,
    const float* __restrict__ b2, const float* __restrict__ W3,
    const float* __restrict__ b3, float* __restrict__ out) {
  __shared__ float oL[256];
  __shared__ float wsum[4];
  int tid = threadIdx.x;
  int p = blockIdx.x >> 5, b = blockIdx.x & 31;
  const float* fa = ws + FSEL_OFF + (size_t)((2 * p) * 32 + b) * 256;
  const float* fb = ws + FSEL_OFF + (size_t)((2 * p + 1) * 32 + b) * 256;
  oL[tid] = fa[tid];
  __syncthreads();
  float a1 = b1[tid], a2 = b2[tid], a3 = b3[tid];
  const float* w1r = W1 + tid * 256;
  const float* w2r = W2 + tid * 256;
  const float* w3r = W3 + tid * 256;
  for (int k = 0; k < 256; k++) {
    float ov = oL[k];
    a1 += ov * w1r[k];
    a2 += ov * w2r[k];
    a3 += ov * w3r[k];
  }
  float cg = sigm(a1) * leaky(a2);
  float res = oL[tid] + sigm(a3) * leaky(cg);
  float d = res - fb[tid] + 1e-6f;
  float sq = d * d;
  for (int m = 32; m >= 1; m >>= 1) sq += __shfl_down(sq, m, 64);
  if ((tid & 63) == 0) wsum[tid >> 6] = sq;
  __syncthreads();
  if (tid == 0) {
    float s = wsum[0] + wsum[1] + wsum[2] + wsum[3];
    out[p * BB + b] = expf(sqrtf(s));
  }
}

extern "C" void kernel_launch(void* const* d_in, const int* in_sizes, int n_in,
                              void* d_out, int out_size, void* d_ws, size_t ws_size,
                              hipStream_t stream) {
  const float* anchor = (const float*)d_in[0];
  const float* trajs = (const float*)d_in[1];
  const float* negat = (const float*)d_in[2];
  const int* la = (const int*)d_in[3];
  const int* lt = (const int*)d_in[4];
  const int* ln = (const int*)d_in[5];
  const float* Wm = (const float*)d_in[6];
  const float* bm = (const float*)d_in[7];
  const float* Wih = (const float*)d_in[8];
  const float* Whh = (const float*)d_in[9];
  const float* bih = (const float*)d_in[10];
  const float* bhh = (const float*)d_in[11];
  const float* W1 = (const float*)d_in[12];
  const float* b1 = (const float*)d_in[13];
  const float* W2 = (const float*)d_in[14];
  const float* b2 = (const float*)d_in[15];
  const float* W3 = (const float*)d_in[16];
  const float* b3 = (const float*)d_in[17];
  float* ws = (float*)d_ws;
  float* out = (float*)d_out;

  embed_kernel<<<(3 * BB * TT * 128) / 256, 256, 0, stream>>>(anchor, trajs, negat, Wm, bm, ws);
  mask_kernel<<<(3 * BB * TT) / 256, 256, 0, stream>>>(anchor, trajs, negat, ws);
  wt_kernel<<<(512 * 1024) / 256, 256, 0, stream>>>(Wih, Whh, ws);
  attn_kernel<<<4096, 256, 0, stream>>>(ws);
  lstm_kernel<<<64, 512, 0, stream>>>(ws, la, lt, ln, bih, bhh);
  finish_kernel<<<64, 256, 0, stream>>>(ws, W1, b1, W2, b2, W3, b3, out);
}